// Round 1
// baseline (149.858 us; speedup 1.0000x reference)
//
#include <hip/hip_runtime.h>
#include <hip/hip_bf16.h>
#include <cstdint>
#include <cstddef>

typedef __bf16 bf16x8 __attribute__((ext_vector_type(8)));
typedef __bf16 bf16x4 __attribute__((ext_vector_type(4)));
typedef float  f32x4  __attribute__((ext_vector_type(4)));

#define D_DIM 1024
#define BM 128
#define BN 128
#define BK 64

#define GLB(p) ((const __attribute__((address_space(1))) void*)(p))
#define LDS(p) ((__attribute__((address_space(3))) void*)(p))

// ---- stage 0: convert x (fp32) -> padded bf16, zero pad rows, zero cnt ----
__global__ __launch_bounds__(256) void conv_x_kernel(
    const float* __restrict__ x, __bf16* __restrict__ xb,
    int* __restrict__ cnt, int N, int MP)
{
    int i = blockIdx.x * 256 + threadIdx.x;      // group of 4 elements
    if (i < N) cnt[i] = 0;                        // zero degree counters
    int total = MP * (D_DIM / 4);
    if (i >= total) return;
    int row = i >> 8;                             // D/4 = 256 groups per row
    size_t base = (size_t)i * 4;
    bf16x4 o;
    if (row < N) {
        float4 v = *(const float4*)(x + base);
        o[0] = (__bf16)v.x; o[1] = (__bf16)v.y; o[2] = (__bf16)v.z; o[3] = (__bf16)v.w;
    } else {
        o[0] = (__bf16)0.f; o[1] = (__bf16)0.f; o[2] = (__bf16)0.f; o[3] = (__bf16)0.f;
    }
    *(bf16x4*)(xb + base) = o;
}

// ---- stage 0b: W [K][N] fp32 -> W^T [N][K] bf16 (tiled transpose) ----
__global__ void transpose_w_kernel(const float* __restrict__ W, __bf16* __restrict__ wT)
{
    __shared__ float tile[32][33];
    int nb = blockIdx.x * 32, kb = blockIdx.y * 32;
    int tx = threadIdx.x, ty = threadIdx.y;      // (32, 8)
    #pragma unroll
    for (int i = 0; i < 32; i += 8)
        tile[ty + i][tx] = W[(size_t)(kb + ty + i) * D_DIM + nb + tx];
    __syncthreads();
    #pragma unroll
    for (int i = 0; i < 32; i += 8)
        wT[(size_t)(nb + ty + i) * D_DIM + kb + tx] = (__bf16)tile[tx][ty + i];
}

// ---- stage 1: degree count over dst ----
__global__ __launch_bounds__(256) void count_kernel(
    const int* __restrict__ dst, int* __restrict__ cnt, int E)
{
    int e = blockIdx.x * 256 + threadIdx.x;
    if (e < E) atomicAdd(&cnt[dst[e]], 1);
}

// ---- stage 2: single-block scan -> row_ptr/cursor, dinv = rsqrt(cnt+1) ----
__global__ __launch_bounds__(1024) void scan_kernel(
    const int* __restrict__ cnt, int* __restrict__ row_ptr,
    int* __restrict__ cursor, float* __restrict__ dinv, int N)
{
    __shared__ int wsum[16];
    __shared__ int sctot;
    int tid = threadIdx.x, lane = tid & 63, wid = tid >> 6;
    int carry = 0;
    int chunks = (N + 1023) >> 10;
    for (int ch = 0; ch < chunks; ++ch) {
        int i = (ch << 10) + tid;
        int c = (i < N) ? cnt[i] : 0;
        int v = c;
        #pragma unroll
        for (int off = 1; off < 64; off <<= 1) {
            int t = __shfl_up(v, off);
            if (lane >= off) v += t;
        }
        if (lane == 63) wsum[wid] = v;
        __syncthreads();
        if (tid < 16) {
            int s = wsum[tid];
            int sv = s;
            #pragma unroll
            for (int off = 1; off < 16; off <<= 1) {
                int t = __shfl_up(sv, off);
                if (tid >= off) sv += t;
            }
            wsum[tid] = sv - s;                  // exclusive wave offset
            if (tid == 15) sctot = sv;
        }
        __syncthreads();
        int incl = carry + wsum[wid] + v;
        if (i < N) {
            int excl = incl - c;
            row_ptr[i] = excl;
            cursor[i]  = excl;
            dinv[i] = rsqrtf((float)c + 1.0f);   // +1 self loop, always > 0
        }
        carry += sctot;
        __syncthreads();
    }
    if (tid == 0) row_ptr[N] = carry;
}

// ---- stage 3: CSR fill ----
__global__ __launch_bounds__(256) void fill_kernel(
    const int* __restrict__ src, const int* __restrict__ dst,
    int* __restrict__ cursor, int* __restrict__ col, int E)
{
    int e = blockIdx.x * 256 + threadIdx.x;
    if (e < E) {
        int d = dst[e];
        int pos = atomicAdd(&cursor[d], 1);
        col[pos] = src[e];
    }
}

// ---- stage 4: h = xb @ W  (bf16 MFMA, 128x128 tile, BK=64, gl_load_lds) ----
__global__ __launch_bounds__(256) void gemm_kernel(
    const __bf16* __restrict__ A,   // [MP][K] bf16
    const __bf16* __restrict__ BT,  // [N][K] bf16 (W transposed)
    __bf16* __restrict__ C,         // [MP][N] bf16
    int K, int N)
{
    __shared__ __bf16 As[BM * BK];
    __shared__ __bf16 Bs[BN * BK];
    int tid = threadIdx.x;
    int wid = tid >> 6, lane = tid & 63;
    int bm = blockIdx.x, bn = blockIdx.y;
    int wr = wid >> 1, wc = wid & 1;             // 2x2 wave grid, 64x64 each
    f32x4 acc[4][4] = {};
    const int ksteps = K / BK;
    for (int ks = 0; ks < ksteps; ++ks) {
        #pragma unroll
        for (int i = 0; i < 4; ++i) {
            int c = i * 256 + wid * 64 + lane;   // 16B chunk id, lane-contiguous
            int row = c >> 3;                    // 8 chunks per 64-elem row
            int kc  = (c & 7) * 8;
            const __bf16* ga = A  + (size_t)(bm * BM + row) * K + ks * BK + kc;
            const __bf16* gb = BT + (size_t)(bn * BN + row) * K + ks * BK + kc;
            __builtin_amdgcn_global_load_lds(GLB(ga), LDS(As + c * 8), 16, 0, 0);
            __builtin_amdgcn_global_load_lds(GLB(gb), LDS(Bs + c * 8), 16, 0, 0);
        }
        asm volatile("s_waitcnt vmcnt(0)" ::: "memory");
        __syncthreads();
        #pragma unroll
        for (int kk = 0; kk < 2; ++kk) {
            bf16x8 af[4], bfr[4];
            int kb = kk * 32 + (lane >> 4) * 8;
            #pragma unroll
            for (int mi = 0; mi < 4; ++mi)
                af[mi] = *(const bf16x8*)(As + (wr * 64 + mi * 16 + (lane & 15)) * BK + kb);
            #pragma unroll
            for (int ni = 0; ni < 4; ++ni)
                bfr[ni] = *(const bf16x8*)(Bs + (wc * 64 + ni * 16 + (lane & 15)) * BK + kb);
            #pragma unroll
            for (int mi = 0; mi < 4; ++mi)
                #pragma unroll
                for (int ni = 0; ni < 4; ++ni)
                    acc[mi][ni] = __builtin_amdgcn_mfma_f32_16x16x32_bf16(
                        af[mi], bfr[ni], acc[mi][ni], 0, 0, 0);
        }
        __syncthreads();
    }
    // C layout: col = lane&15, row = (lane>>4)*4 + r   [m89-verified]
    #pragma unroll
    for (int mi = 0; mi < 4; ++mi)
        #pragma unroll
        for (int ni = 0; ni < 4; ++ni)
            #pragma unroll
            for (int r = 0; r < 4; ++r) {
                int row = bm * BM + wr * 64 + mi * 16 + (lane >> 4) * 4 + r;
                int colc = bn * BN + wc * 64 + ni * 16 + (lane & 15);
                C[(size_t)row * N + colc] = (__bf16)acc[mi][ni][r];
            }
}

// ---- stage 5: per-dst-row gather-accumulate + bias + ReLU ----
__global__ __launch_bounds__(256) void scatter_kernel(
    const __bf16* __restrict__ h, const int* __restrict__ row_ptr,
    const int* __restrict__ col, const float* __restrict__ dinv,
    const float* __restrict__ b, float* __restrict__ out)
{
    int d = blockIdx.x;
    int tid = threadIdx.x;
    int cbase = tid * 4;
    float dv = dinv[d];
    float acc[4];
    // self loop: h[d] * dinv[d]^2
    bf16x4 v = *(const bf16x4*)(h + (size_t)d * D_DIM + cbase);
    float sw = dv * dv;
    #pragma unroll
    for (int j = 0; j < 4; ++j) acc[j] = (float)v[j] * sw;
    int r0 = row_ptr[d], r1 = row_ptr[d + 1];
    for (int e = r0; e < r1; ++e) {
        int s = col[e];
        float w = dinv[s] * dv;
        bf16x4 u = *(const bf16x4*)(h + (size_t)s * D_DIM + cbase);
        #pragma unroll
        for (int j = 0; j < 4; ++j) acc[j] = fmaf((float)u[j], w, acc[j]);
    }
    float4 bb = *(const float4*)(b + cbase);
    float4 o;
    o.x = fmaxf(acc[0] + bb.x, 0.f);
    o.y = fmaxf(acc[1] + bb.y, 0.f);
    o.z = fmaxf(acc[2] + bb.z, 0.f);
    o.w = fmaxf(acc[3] + bb.w, 0.f);
    *(float4*)(out + (size_t)d * D_DIM + cbase) = o;
}

extern "C" void kernel_launch(void* const* d_in, const int* in_sizes, int n_in,
                              void* d_out, int out_size, void* d_ws, size_t ws_size,
                              hipStream_t stream)
{
    const float* x  = (const float*)d_in[0];
    const int*   ei = (const int*)d_in[1];
    const float* W  = (const float*)d_in[2];
    const float* b  = (const float*)d_in[3];
    float* out = (float*)d_out;

    const int N = in_sizes[0] / D_DIM;     // 10000
    const int E = in_sizes[1] / 2;         // 160000
    const int MP = ((N + BM - 1) / BM) * BM; // 10112
    const int K = D_DIM;

    const int* src = ei;
    const int* dst = ei + E;

    // ws bump allocator, 256B aligned
    char* ws = (char*)d_ws;
    size_t off = 0;
    auto alloc = [&](size_t bytes) -> char* {
        char* p = ws + off;
        off += (bytes + 255) & ~(size_t)255;
        return p;
    };
    __bf16* xb     = (__bf16*)alloc((size_t)MP * D_DIM * 2);
    __bf16* wT     = (__bf16*)alloc((size_t)D_DIM * D_DIM * 2);
    __bf16* h      = (__bf16*)alloc((size_t)MP * D_DIM * 2);
    int*    cnt    = (int*)alloc((size_t)N * 4);
    int*    rowptr = (int*)alloc((size_t)(N + 1) * 4);
    int*    cursor = (int*)alloc((size_t)N * 4);
    int*    colbuf = (int*)alloc((size_t)E * 4);
    float*  dinv   = (float*)alloc((size_t)N * 4);
    (void)ws_size;

    // 0: convert x -> padded bf16 (also zeroes cnt)
    int groups = MP * (D_DIM / 4);
    conv_x_kernel<<<(groups + 255) / 256, 256, 0, stream>>>(x, xb, cnt, N, MP);
    // 0b: W -> W^T bf16
    transpose_w_kernel<<<dim3(D_DIM / 32, D_DIM / 32), dim3(32, 8), 0, stream>>>(W, wT);
    // 1: degree count
    count_kernel<<<(E + 255) / 256, 256, 0, stream>>>(dst, cnt, E);
    // 2: scan -> row_ptr, cursor, dinv
    scan_kernel<<<1, 1024, 0, stream>>>(cnt, rowptr, cursor, dinv, N);
    // 3: CSR fill
    fill_kernel<<<(E + 255) / 256, 256, 0, stream>>>(src, dst, cursor, colbuf, E);
    // 4: h = xb @ W (bf16 MFMA)
    gemm_kernel<<<dim3(MP / BM, D_DIM / BN), 256, 0, stream>>>(xb, wT, h, K, D_DIM);
    // 5: gather-accumulate + bias + relu
    scatter_kernel<<<N, 256, 0, stream>>>(h, rowptr, colbuf, dinv, b, out);
}

// Round 2
// 147.399 us; speedup vs baseline: 1.0167x; 1.0167x over previous
//
#include <hip/hip_runtime.h>
#include <hip/hip_bf16.h>
#include <cstdint>
#include <cstddef>

typedef __bf16 bf16x8 __attribute__((ext_vector_type(8)));
typedef __bf16 bf16x4 __attribute__((ext_vector_type(4)));
typedef float  f32x4  __attribute__((ext_vector_type(4)));

#define D_DIM 1024
#define BM 128
#define BN 128
#define BK 64
#define NXCD 8

#define GLB(p) ((const __attribute__((address_space(1))) void*)(p))
#define LDS(p) ((__attribute__((address_space(3))) void*)(p))

// ---- stage 0: convert x (fp32) -> padded bf16, zero pad rows, zero cnt ----
__global__ __launch_bounds__(256) void conv_x_kernel(
    const float* __restrict__ x, __bf16* __restrict__ xb,
    int* __restrict__ cnt, int N, int MP)
{
    int i = blockIdx.x * 256 + threadIdx.x;      // group of 4 elements
    if (i < N) cnt[i] = 0;                        // zero degree counters
    int total = MP * (D_DIM / 4);
    if (i >= total) return;
    int row = i >> 8;                             // D/4 = 256 groups per row
    size_t base = (size_t)i * 4;
    bf16x4 o;
    if (row < N) {
        float4 v = *(const float4*)(x + base);
        o[0] = (__bf16)v.x; o[1] = (__bf16)v.y; o[2] = (__bf16)v.z; o[3] = (__bf16)v.w;
    } else {
        o[0] = (__bf16)0.f; o[1] = (__bf16)0.f; o[2] = (__bf16)0.f; o[3] = (__bf16)0.f;
    }
    *(bf16x4*)(xb + base) = o;
}

// ---- stage 0b: W [K][N] fp32 -> W^T [N][K] bf16 (tiled transpose) ----
__global__ void transpose_w_kernel(const float* __restrict__ W, __bf16* __restrict__ wT)
{
    __shared__ float tile[32][33];
    int nb = blockIdx.x * 32, kb = blockIdx.y * 32;
    int tx = threadIdx.x, ty = threadIdx.y;      // (32, 8)
    #pragma unroll
    for (int i = 0; i < 32; i += 8)
        tile[ty + i][tx] = W[(size_t)(kb + ty + i) * D_DIM + nb + tx];
    __syncthreads();
    #pragma unroll
    for (int i = 0; i < 32; i += 8)
        wT[(size_t)(nb + ty + i) * D_DIM + kb + tx] = (__bf16)tile[tx][ty + i];
}

// ---- stage 1: degree count over dst ----
__global__ __launch_bounds__(256) void count_kernel(
    const int* __restrict__ dst, int* __restrict__ cnt, int E)
{
    int e = blockIdx.x * 256 + threadIdx.x;
    if (e < E) atomicAdd(&cnt[dst[e]], 1);
}

// ---- stage 2: single-block scan (LDS-prefetched) -> row_ptr/cursor/dinv ----
__global__ __launch_bounds__(1024) void scan_kernel(
    const int* __restrict__ cnt, int* __restrict__ row_ptr,
    int* __restrict__ cursor, float* __restrict__ dinv, int N)
{
    __shared__ int sbuf[10240];                  // N <= 10240
    __shared__ int wsum[16];
    __shared__ int sctot;
    int tid = threadIdx.x, lane = tid & 63, wid = tid >> 6;
    int chunks = (N + 1023) >> 10;
    // prefetch everything: all loads issued before first use
    #pragma unroll 4
    for (int ch = 0; ch < chunks; ++ch) {
        int i = (ch << 10) + tid;
        sbuf[(ch << 10) + tid] = (i < N) ? cnt[i] : 0;
    }
    __syncthreads();
    int carry = 0;
    for (int ch = 0; ch < chunks; ++ch) {
        int i = (ch << 10) + tid;
        int c = sbuf[(ch << 10) + tid];
        int v = c;
        #pragma unroll
        for (int off = 1; off < 64; off <<= 1) {
            int t = __shfl_up(v, off);
            if (lane >= off) v += t;
        }
        if (lane == 63) wsum[wid] = v;
        __syncthreads();
        if (tid < 16) {
            int s = wsum[tid];
            int sv = s;
            #pragma unroll
            for (int off = 1; off < 16; off <<= 1) {
                int t = __shfl_up(sv, off);
                if (tid >= off) sv += t;
            }
            wsum[tid] = sv - s;                  // exclusive wave offset
            if (tid == 15) sctot = sv;
        }
        __syncthreads();
        int incl = carry + wsum[wid] + v;
        if (i < N) {
            int excl = incl - c;
            row_ptr[i] = excl;
            cursor[i]  = excl;
            dinv[i] = rsqrtf((float)c + 1.0f);   // +1 self loop, always > 0
        }
        carry += sctot;
        __syncthreads();
    }
    if (tid == 0) row_ptr[N] = carry;
}

// ---- stage 3: CSR fill ----
__global__ __launch_bounds__(256) void fill_kernel(
    const int* __restrict__ src, const int* __restrict__ dst,
    int* __restrict__ cursor, int* __restrict__ col, int E)
{
    int e = blockIdx.x * 256 + threadIdx.x;
    if (e < E) {
        int d = dst[e];
        int pos = atomicAdd(&cursor[d], 1);
        col[pos] = src[e];
    }
}

// ---- stage 4: h = xb @ W  (bf16 MFMA, 128x128 tile, XCD-chunked remap) ----
// Block remap: assume dispatch round-robins XCDs (xcd = wg % 8). Give each
// XCD a contiguous chunk of bm rows x ALL bn columns so the A-tile is
// fetched once into that XCD's L2 and reused by all 8 bn-blocks.
__global__ __launch_bounds__(256) void gemm_kernel(
    const __bf16* __restrict__ A,   // [MP][K] bf16
    const __bf16* __restrict__ BT,  // [N][K] bf16 (W transposed)
    __bf16* __restrict__ C,         // [MP][N] bf16
    int K, int N, int mtiles, int ntiles, int chunk)
{
    __shared__ __bf16 As[BM * BK];
    __shared__ __bf16 Bs[BN * BK];
    int wg = blockIdx.x;
    int c8 = wg & (NXCD - 1);
    int r  = wg >> 3;
    int bm = c8 * chunk + r / ntiles;
    int bn = r % ntiles;
    if (bm >= mtiles) return;

    int tid = threadIdx.x;
    int wid = tid >> 6, lane = tid & 63;
    int wr = wid >> 1, wc = wid & 1;             // 2x2 wave grid, 64x64 each
    f32x4 acc[4][4] = {};
    const int ksteps = K / BK;
    for (int ks = 0; ks < ksteps; ++ks) {
        #pragma unroll
        for (int i = 0; i < 4; ++i) {
            int c = i * 256 + wid * 64 + lane;   // 16B chunk id, lane-contiguous
            int row = c >> 3;                    // 8 chunks per 64-elem row
            int kc  = (c & 7) * 8;
            const __bf16* ga = A  + (size_t)(bm * BM + row) * K + ks * BK + kc;
            const __bf16* gb = BT + (size_t)(bn * BN + row) * K + ks * BK + kc;
            __builtin_amdgcn_global_load_lds(GLB(ga), LDS(As + c * 8), 16, 0, 0);
            __builtin_amdgcn_global_load_lds(GLB(gb), LDS(Bs + c * 8), 16, 0, 0);
        }
        asm volatile("s_waitcnt vmcnt(0)" ::: "memory");
        __syncthreads();
        #pragma unroll
        for (int kk = 0; kk < 2; ++kk) {
            bf16x8 af[4], bfr[4];
            int kb = kk * 32 + (lane >> 4) * 8;
            #pragma unroll
            for (int mi = 0; mi < 4; ++mi)
                af[mi] = *(const bf16x8*)(As + (wr * 64 + mi * 16 + (lane & 15)) * BK + kb);
            #pragma unroll
            for (int ni = 0; ni < 4; ++ni)
                bfr[ni] = *(const bf16x8*)(Bs + (wc * 64 + ni * 16 + (lane & 15)) * BK + kb);
            #pragma unroll
            for (int mi = 0; mi < 4; ++mi)
                #pragma unroll
                for (int ni = 0; ni < 4; ++ni)
                    acc[mi][ni] = __builtin_amdgcn_mfma_f32_16x16x32_bf16(
                        af[mi], bfr[ni], acc[mi][ni], 0, 0, 0);
        }
        __syncthreads();
    }
    // C layout: col = lane&15, row = (lane>>4)*4 + r   [m89-verified]
    #pragma unroll
    for (int mi = 0; mi < 4; ++mi)
        #pragma unroll
        for (int ni = 0; ni < 4; ++ni)
            #pragma unroll
            for (int rr = 0; rr < 4; ++rr) {
                int row = bm * BM + wr * 64 + mi * 16 + (lane >> 4) * 4 + rr;
                int colc = bn * BN + wc * 64 + ni * 16 + (lane & 15);
                C[(size_t)row * N + colc] = (__bf16)acc[mi][ni][rr];
            }
}

// ---- stage 5: per-dst-row gather-accumulate + bias + ReLU ----
__global__ __launch_bounds__(256) void scatter_kernel(
    const __bf16* __restrict__ h, const int* __restrict__ row_ptr,
    const int* __restrict__ col, const float* __restrict__ dinv,
    const float* __restrict__ b, float* __restrict__ out)
{
    int d = blockIdx.x;
    int tid = threadIdx.x;
    int cbase = tid * 4;
    float dv = dinv[d];
    float acc[4];
    // self loop: h[d] * dinv[d]^2
    bf16x4 v = *(const bf16x4*)(h + (size_t)d * D_DIM + cbase);
    float sw = dv * dv;
    #pragma unroll
    for (int j = 0; j < 4; ++j) acc[j] = (float)v[j] * sw;
    int r0 = row_ptr[d], r1 = row_ptr[d + 1];
    int e = r0;
    for (; e + 1 < r1; e += 2) {                 // 2-way unroll for load ILP
        int s0 = col[e], s1 = col[e + 1];
        float w0 = dinv[s0] * dv, w1 = dinv[s1] * dv;
        bf16x4 u0 = *(const bf16x4*)(h + (size_t)s0 * D_DIM + cbase);
        bf16x4 u1 = *(const bf16x4*)(h + (size_t)s1 * D_DIM + cbase);
        #pragma unroll
        for (int j = 0; j < 4; ++j) acc[j] = fmaf((float)u0[j], w0, acc[j]);
        #pragma unroll
        for (int j = 0; j < 4; ++j) acc[j] = fmaf((float)u1[j], w1, acc[j]);
    }
    if (e < r1) {
        int s = col[e];
        float w = dinv[s] * dv;
        bf16x4 u = *(const bf16x4*)(h + (size_t)s * D_DIM + cbase);
        #pragma unroll
        for (int j = 0; j < 4; ++j) acc[j] = fmaf((float)u[j], w, acc[j]);
    }
    float4 bb = *(const float4*)(b + cbase);
    float4 o;
    o.x = fmaxf(acc[0] + bb.x, 0.f);
    o.y = fmaxf(acc[1] + bb.y, 0.f);
    o.z = fmaxf(acc[2] + bb.z, 0.f);
    o.w = fmaxf(acc[3] + bb.w, 0.f);
    *(float4*)(out + (size_t)d * D_DIM + cbase) = o;
}

extern "C" void kernel_launch(void* const* d_in, const int* in_sizes, int n_in,
                              void* d_out, int out_size, void* d_ws, size_t ws_size,
                              hipStream_t stream)
{
    const float* x  = (const float*)d_in[0];
    const int*   ei = (const int*)d_in[1];
    const float* W  = (const float*)d_in[2];
    const float* b  = (const float*)d_in[3];
    float* out = (float*)d_out;

    const int N = in_sizes[0] / D_DIM;     // 10000
    const int E = in_sizes[1] / 2;         // 160000
    const int MP = ((N + BM - 1) / BM) * BM; // 10112
    const int K = D_DIM;

    const int* src = ei;
    const int* dst = ei + E;

    // ws bump allocator, 256B aligned
    char* ws = (char*)d_ws;
    size_t off = 0;
    auto alloc = [&](size_t bytes) -> char* {
        char* p = ws + off;
        off += (bytes + 255) & ~(size_t)255;
        return p;
    };
    __bf16* xb     = (__bf16*)alloc((size_t)MP * D_DIM * 2);
    __bf16* wT     = (__bf16*)alloc((size_t)D_DIM * D_DIM * 2);
    __bf16* h      = (__bf16*)alloc((size_t)MP * D_DIM * 2);
    int*    cnt    = (int*)alloc((size_t)N * 4);
    int*    rowptr = (int*)alloc((size_t)(N + 1) * 4);
    int*    cursor = (int*)alloc((size_t)N * 4);
    int*    colbuf = (int*)alloc((size_t)E * 4);
    float*  dinv   = (float*)alloc((size_t)N * 4);
    (void)ws_size;

    // 0: convert x -> padded bf16 (also zeroes cnt)
    int groups = MP * (D_DIM / 4);
    conv_x_kernel<<<(groups + 255) / 256, 256, 0, stream>>>(x, xb, cnt, N, MP);
    // 0b: W -> W^T bf16
    transpose_w_kernel<<<dim3(D_DIM / 32, D_DIM / 32), dim3(32, 8), 0, stream>>>(W, wT);
    // 1: degree count
    count_kernel<<<(E + 255) / 256, 256, 0, stream>>>(dst, cnt, E);
    // 2: scan -> row_ptr, cursor, dinv
    scan_kernel<<<1, 1024, 0, stream>>>(cnt, rowptr, cursor, dinv, N);
    // 3: CSR fill
    fill_kernel<<<(E + 255) / 256, 256, 0, stream>>>(src, dst, cursor, colbuf, E);
    // 4: h = xb @ W (bf16 MFMA) — XCD-chunked remap
    int mtiles = MP / BM;                      // 79
    int ntiles = D_DIM / BN;                   // 8
    int chunk  = (mtiles + NXCD - 1) / NXCD;   // 10
    int nblocks = NXCD * chunk * ntiles;       // 640 (8 early-exit)
    gemm_kernel<<<nblocks, 256, 0, stream>>>(xb, wT, h, K, D_DIM, mtiles, ntiles, chunk);
    // 5: gather-accumulate + bias + relu
    scatter_kernel<<<N, 256, 0, stream>>>(h, rowptr, colbuf, dinv, b, out);
}

// Round 3
// 129.697 us; speedup vs baseline: 1.1554x; 1.1365x over previous
//
#include <hip/hip_runtime.h>
#include <hip/hip_bf16.h>
#include <cstdint>
#include <cstddef>

typedef __bf16 bf16x8 __attribute__((ext_vector_type(8)));
typedef __bf16 bf16x4 __attribute__((ext_vector_type(4)));
typedef float  f32x4  __attribute__((ext_vector_type(4)));

#define D_DIM 1024
#define BM 128
#define BN 128
#define BK 64
#define NXCD 8

#define GLB(p) ((const __attribute__((address_space(1))) void*)(p))
#define LDS(p) ((__attribute__((address_space(3))) void*)(p))

// ---- stage 0: convert x (fp32) -> padded bf16, zero pad rows, zero cnt ----
__global__ __launch_bounds__(256) void conv_x_kernel(
    const float* __restrict__ x, __bf16* __restrict__ xb,
    int* __restrict__ cnt, int N, int MP)
{
    int i = blockIdx.x * 256 + threadIdx.x;      // group of 4 elements
    if (i < N) cnt[i] = 0;                        // zero degree counters
    int total = MP * (D_DIM / 4);
    if (i >= total) return;
    int row = i >> 8;                             // D/4 = 256 groups per row
    size_t base = (size_t)i * 4;
    bf16x4 o;
    if (row < N) {
        float4 v = *(const float4*)(x + base);
        o[0] = (__bf16)v.x; o[1] = (__bf16)v.y; o[2] = (__bf16)v.z; o[3] = (__bf16)v.w;
    } else {
        o[0] = (__bf16)0.f; o[1] = (__bf16)0.f; o[2] = (__bf16)0.f; o[3] = (__bf16)0.f;
    }
    *(bf16x4*)(xb + base) = o;
}

// ---- stage 0b: W [K][N] fp32 -> W^T [N][K] bf16 (tiled transpose) ----
__global__ void transpose_w_kernel(const float* __restrict__ W, __bf16* __restrict__ wT)
{
    __shared__ float tile[32][33];
    int nb = blockIdx.x * 32, kb = blockIdx.y * 32;
    int tx = threadIdx.x, ty = threadIdx.y;      // (32, 8)
    #pragma unroll
    for (int i = 0; i < 32; i += 8)
        tile[ty + i][tx] = W[(size_t)(kb + ty + i) * D_DIM + nb + tx];
    __syncthreads();
    #pragma unroll
    for (int i = 0; i < 32; i += 8)
        wT[(size_t)(nb + ty + i) * D_DIM + kb + tx] = (__bf16)tile[tx][ty + i];
}

// ---- stage 1: degree count over dst ----
__global__ __launch_bounds__(256) void count_kernel(
    const int* __restrict__ dst, int* __restrict__ cnt, int E)
{
    int e = blockIdx.x * 256 + threadIdx.x;
    if (e < E) atomicAdd(&cnt[dst[e]], 1);
}

// ---- stage 2: single-block scan (LDS-prefetched) -> row_ptr/cursor/dinv ----
__global__ __launch_bounds__(1024) void scan_kernel(
    const int* __restrict__ cnt, int* __restrict__ row_ptr,
    int* __restrict__ cursor, float* __restrict__ dinv, int N)
{
    __shared__ int sbuf[10240];                  // N <= 10240
    __shared__ int wsum[16];
    __shared__ int sctot;
    int tid = threadIdx.x, lane = tid & 63, wid = tid >> 6;
    int chunks = (N + 1023) >> 10;
    #pragma unroll 4
    for (int ch = 0; ch < chunks; ++ch) {
        int i = (ch << 10) + tid;
        sbuf[(ch << 10) + tid] = (i < N) ? cnt[i] : 0;
    }
    __syncthreads();
    int carry = 0;
    for (int ch = 0; ch < chunks; ++ch) {
        int i = (ch << 10) + tid;
        int c = sbuf[(ch << 10) + tid];
        int v = c;
        #pragma unroll
        for (int off = 1; off < 64; off <<= 1) {
            int t = __shfl_up(v, off);
            if (lane >= off) v += t;
        }
        if (lane == 63) wsum[wid] = v;
        __syncthreads();
        if (tid < 16) {
            int s = wsum[tid];
            int sv = s;
            #pragma unroll
            for (int off = 1; off < 16; off <<= 1) {
                int t = __shfl_up(sv, off);
                if (tid >= off) sv += t;
            }
            wsum[tid] = sv - s;                  // exclusive wave offset
            if (tid == 15) sctot = sv;
        }
        __syncthreads();
        int incl = carry + wsum[wid] + v;
        if (i < N) {
            int excl = incl - c;
            row_ptr[i] = excl;
            cursor[i]  = excl;
            dinv[i] = rsqrtf((float)c + 1.0f);   // +1 self loop, always > 0
        }
        carry += sctot;
        __syncthreads();
    }
    if (tid == 0) row_ptr[N] = carry;
}

// ---- stage 3: CSR fill ----
__global__ __launch_bounds__(256) void fill_kernel(
    const int* __restrict__ src, const int* __restrict__ dst,
    int* __restrict__ cursor, int* __restrict__ col, int E)
{
    int e = blockIdx.x * 256 + threadIdx.x;
    if (e < E) {
        int d = dst[e];
        int pos = atomicAdd(&cursor[d], 1);
        col[pos] = src[e];
    }
}

// ---- stage 4: h = xb @ W ----
// 128x128 tile, BK=64, XCD-chunked remap, 2-phase prefetch (double-buffered
// LDS, stage t+1 before compute t), T2 XOR-swizzle via inverse-swizzled
// GLOBAL source + linear LDS dest (global_load_lds constraint) + swizzled
// ds_read. Swizzle: 16B-chunk j within row -> j ^ (row & 7). Involution;
// row bits (byte>=7) untouched. Read conflicts drop 16-way -> 2-way (free).
__global__ __launch_bounds__(256) void gemm_kernel(
    const __bf16* __restrict__ A,   // [MP][K] bf16
    const __bf16* __restrict__ BT,  // [N][K] bf16 (W transposed)
    __bf16* __restrict__ C,         // [MP][N] bf16
    int K, int N, int mtiles, int ntiles, int chunk)
{
    __shared__ __bf16 As0[BM * BK], Bs0[BN * BK];
    __shared__ __bf16 As1[BM * BK], Bs1[BN * BK];

    int wg = blockIdx.x;
    int c8 = wg & (NXCD - 1);
    int r  = wg >> 3;
    int bm = c8 * chunk + r / ntiles;
    int bn = r % ntiles;
    if (bm >= mtiles) return;

    int tid = threadIdx.x;
    int wid = tid >> 6, lane = tid & 63;
    int wr = wid >> 1, wc = wid & 1;             // 2x2 wave grid, 64x64 each

    auto stage = [&](int ks, __bf16* dA, __bf16* dB) {
        #pragma unroll
        for (int i = 0; i < 4; ++i) {
            int c   = i * 256 + wid * 64 + lane; // 16B chunk id, lane-contiguous
            int row = c >> 3;                    // 8 chunks per 64-elem row
            int js  = (c & 7) ^ (row & 7);       // inverse-swizzled source chunk
            const __bf16* ga = A  + (size_t)(bm * BM + row) * K + ks * BK + js * 8;
            const __bf16* gb = BT + (size_t)(bn * BN + row) * K + ks * BK + js * 8;
            __builtin_amdgcn_global_load_lds(GLB(ga), LDS(dA + c * 8), 16, 0, 0);
            __builtin_amdgcn_global_load_lds(GLB(gb), LDS(dB + c * 8), 16, 0, 0);
        }
    };

    f32x4 acc[4][4] = {};
    const int ksteps = K / BK;

    __bf16 *rdA = As0, *rdB = Bs0, *wrA = As1, *wrB = Bs1;
    stage(0, rdA, rdB);
    asm volatile("s_waitcnt vmcnt(0)" ::: "memory");
    __syncthreads();

    for (int ks = 0; ks < ksteps; ++ks) {
        if (ks + 1 < ksteps) stage(ks + 1, wrA, wrB);   // prefetch next tile
        #pragma unroll
        for (int kk = 0; kk < 2; ++kk) {
            bf16x8 af[4], bfr[4];
            int jgrp = kk * 4 + (lane >> 4);             // chunk index 0..7
            #pragma unroll
            for (int mi = 0; mi < 4; ++mi) {
                int rr = wr * 64 + mi * 16 + (lane & 15);
                af[mi] = *(const bf16x8*)(rdA + rr * BK + ((jgrp ^ (rr & 7)) << 3));
            }
            #pragma unroll
            for (int ni = 0; ni < 4; ++ni) {
                int rr = wc * 64 + ni * 16 + (lane & 15);
                bfr[ni] = *(const bf16x8*)(rdB + rr * BK + ((jgrp ^ (rr & 7)) << 3));
            }
            #pragma unroll
            for (int mi = 0; mi < 4; ++mi)
                #pragma unroll
                for (int ni = 0; ni < 4; ++ni)
                    acc[mi][ni] = __builtin_amdgcn_mfma_f32_16x16x32_bf16(
                        af[mi], bfr[ni], acc[mi][ni], 0, 0, 0);
        }
        asm volatile("s_waitcnt vmcnt(0)" ::: "memory");  // prefetch landed
        __syncthreads();                                   // all waves done reading rd
        __bf16* t;
        t = rdA; rdA = wrA; wrA = t;
        t = rdB; rdB = wrB; wrB = t;
    }

    // C layout: col = lane&15, row = (lane>>4)*4 + r   [m89-verified]
    #pragma unroll
    for (int mi = 0; mi < 4; ++mi)
        #pragma unroll
        for (int ni = 0; ni < 4; ++ni)
            #pragma unroll
            for (int rr = 0; rr < 4; ++rr) {
                int row = bm * BM + wr * 64 + mi * 16 + (lane >> 4) * 4 + rr;
                int colc = bn * BN + wc * 64 + ni * 16 + (lane & 15);
                C[(size_t)row * N + colc] = (__bf16)acc[mi][ni][rr];
            }
}

// ---- stage 5: gather-accumulate + bias + ReLU ----
// 2 dst rows per 256-thread block; 128 lanes x bf16x8 (16B) per row;
// 4-deep unrolled gather (4KB in flight per wave); LDS remap for fully
// coalesced fp32 output stores.
__global__ __launch_bounds__(256) void scatter_kernel(
    const __bf16* __restrict__ h, const int* __restrict__ row_ptr,
    const int* __restrict__ col, const float* __restrict__ dinv,
    const float* __restrict__ b, float* __restrict__ out, int N)
{
    __shared__ float obuf[2][D_DIM];
    int half = threadIdx.x >> 7;                 // row selector within block
    int t    = threadIdx.x & 127;
    int d    = blockIdx.x * 2 + half;
    int cbase = t * 8;

    if (d < N) {
        float dv = dinv[d];
        float acc[8];
        bf16x8 v = *(const bf16x8*)(h + (size_t)d * D_DIM + cbase);
        float sw = dv * dv;                      // self loop
        #pragma unroll
        for (int j = 0; j < 8; ++j) acc[j] = (float)v[j] * sw;

        int r0 = row_ptr[d], r1 = row_ptr[d + 1];
        int e = r0;
        for (; e + 3 < r1; e += 4) {
            int s0 = col[e], s1 = col[e + 1], s2 = col[e + 2], s3 = col[e + 3];
            float w0 = dinv[s0] * dv, w1 = dinv[s1] * dv;
            float w2 = dinv[s2] * dv, w3 = dinv[s3] * dv;
            bf16x8 u0 = *(const bf16x8*)(h + (size_t)s0 * D_DIM + cbase);
            bf16x8 u1 = *(const bf16x8*)(h + (size_t)s1 * D_DIM + cbase);
            bf16x8 u2 = *(const bf16x8*)(h + (size_t)s2 * D_DIM + cbase);
            bf16x8 u3 = *(const bf16x8*)(h + (size_t)s3 * D_DIM + cbase);
            #pragma unroll
            for (int j = 0; j < 8; ++j) acc[j] = fmaf((float)u0[j], w0, acc[j]);
            #pragma unroll
            for (int j = 0; j < 8; ++j) acc[j] = fmaf((float)u1[j], w1, acc[j]);
            #pragma unroll
            for (int j = 0; j < 8; ++j) acc[j] = fmaf((float)u2[j], w2, acc[j]);
            #pragma unroll
            for (int j = 0; j < 8; ++j) acc[j] = fmaf((float)u3[j], w3, acc[j]);
        }
        for (; e < r1; ++e) {
            int s = col[e];
            float w = dinv[s] * dv;
            bf16x8 u = *(const bf16x8*)(h + (size_t)s * D_DIM + cbase);
            #pragma unroll
            for (int j = 0; j < 8; ++j) acc[j] = fmaf((float)u[j], w, acc[j]);
        }
        float4 b0 = *(const float4*)(b + cbase);
        float4 b1 = *(const float4*)(b + cbase + 4);
        obuf[half][cbase + 0] = fmaxf(acc[0] + b0.x, 0.f);
        obuf[half][cbase + 1] = fmaxf(acc[1] + b0.y, 0.f);
        obuf[half][cbase + 2] = fmaxf(acc[2] + b0.z, 0.f);
        obuf[half][cbase + 3] = fmaxf(acc[3] + b0.w, 0.f);
        obuf[half][cbase + 4] = fmaxf(acc[4] + b1.x, 0.f);
        obuf[half][cbase + 5] = fmaxf(acc[5] + b1.y, 0.f);
        obuf[half][cbase + 6] = fmaxf(acc[6] + b1.z, 0.f);
        obuf[half][cbase + 7] = fmaxf(acc[7] + b1.w, 0.f);
    }
    __syncthreads();
    int d0 = blockIdx.x * 2;
    #pragma unroll
    for (int rsel = 0; rsel < 2; ++rsel) {
        int dd = d0 + rsel;
        if (dd < N) {
            float4 vv = *(const float4*)&obuf[rsel][threadIdx.x * 4];
            *(float4*)(out + (size_t)dd * D_DIM + threadIdx.x * 4) = vv;
        }
    }
}

extern "C" void kernel_launch(void* const* d_in, const int* in_sizes, int n_in,
                              void* d_out, int out_size, void* d_ws, size_t ws_size,
                              hipStream_t stream)
{
    const float* x  = (const float*)d_in[0];
    const int*   ei = (const int*)d_in[1];
    const float* W  = (const float*)d_in[2];
    const float* b  = (const float*)d_in[3];
    float* out = (float*)d_out;

    const int N = in_sizes[0] / D_DIM;     // 10000
    const int E = in_sizes[1] / 2;         // 160000
    const int MP = ((N + BM - 1) / BM) * BM; // 10112
    const int K = D_DIM;

    const int* src = ei;
    const int* dst = ei + E;

    // ws bump allocator, 256B aligned
    char* ws = (char*)d_ws;
    size_t off = 0;
    auto alloc = [&](size_t bytes) -> char* {
        char* p = ws + off;
        off += (bytes + 255) & ~(size_t)255;
        return p;
    };
    __bf16* xb     = (__bf16*)alloc((size_t)MP * D_DIM * 2);
    __bf16* wT     = (__bf16*)alloc((size_t)D_DIM * D_DIM * 2);
    __bf16* h      = (__bf16*)alloc((size_t)MP * D_DIM * 2);
    int*    cnt    = (int*)alloc((size_t)N * 4);
    int*    rowptr = (int*)alloc((size_t)(N + 1) * 4);
    int*    cursor = (int*)alloc((size_t)N * 4);
    int*    colbuf = (int*)alloc((size_t)E * 4);
    float*  dinv   = (float*)alloc((size_t)N * 4);
    (void)ws_size;

    // 0: convert x -> padded bf16 (also zeroes cnt)
    int groups = MP * (D_DIM / 4);
    conv_x_kernel<<<(groups + 255) / 256, 256, 0, stream>>>(x, xb, cnt, N, MP);
    // 0b: W -> W^T bf16
    transpose_w_kernel<<<dim3(D_DIM / 32, D_DIM / 32), dim3(32, 8), 0, stream>>>(W, wT);
    // 1: degree count
    count_kernel<<<(E + 255) / 256, 256, 0, stream>>>(dst, cnt, E);
    // 2: scan -> row_ptr, cursor, dinv
    scan_kernel<<<1, 1024, 0, stream>>>(cnt, rowptr, cursor, dinv, N);
    // 3: CSR fill
    fill_kernel<<<(E + 255) / 256, 256, 0, stream>>>(src, dst, cursor, colbuf, E);
    // 4: h = xb @ W (bf16 MFMA) — XCD-chunked + 2-phase prefetch + swizzle
    int mtiles = MP / BM;                      // 79
    int ntiles = D_DIM / BN;                   // 8
    int chunk  = (mtiles + NXCD - 1) / NXCD;   // 10
    int nblocks = NXCD * chunk * ntiles;       // 640 (8 early-exit)
    gemm_kernel<<<nblocks, 256, 0, stream>>>(xb, wT, h, K, D_DIM, mtiles, ntiles, chunk);
    // 5: gather-accumulate + bias + relu
    scatter_kernel<<<(N + 1) / 2, 256, 0, stream>>>(h, rowptr, colbuf, dinv, b, out, N);
}